// Round 10
// baseline (119.243 us; speedup 1.0000x reference)
//
#include <hip/hip_runtime.h>

// MultiHeadDense: out[b] = x[b] @ W[idx[b]] + bias[idx[b]]
// B=4096, D=1024, F=1024, H=8. fp32 in/out; bf16 MFMA internally.
// Round 10: step-slot law: time ~ slots/CU x 310ns when >=3 independent
// blocks co-resident; ~1.2us when <3. So: 64x64 tile, BK=128 (8 steps),
// 1024 working blocks (4/CU), SINGLE 32KB LDS buffer (capacity 5) with
// register-bounce staging (swizzled ds_write; Ap/Wt stay plain row-major).
// Full K per block -> plain stores + bias (no atomics).

typedef __attribute__((ext_vector_type(8))) short bf16x8;
typedef __attribute__((ext_vector_type(4))) float f32x4;

static __device__ __forceinline__ unsigned short f2bf(float f) {
  union { float f; unsigned int u; } c; c.f = f;
  unsigned int u = c.u;
  return (unsigned short)((u + 0x7fffu + ((u >> 16) & 1u)) >> 16);
}

// Kernel 1 (fused): blocks 0..2047 transpose+convert W [H][D][F] fp32 ->
// Wt [H][F][D] bf16 (plain row-major). Block 2048: counting-sort scan of
// idx -> rows[] + cnt[] + base8[] (8-aligned head bases; gaps zero-filled).
__global__ __launch_bounds__(256) void k_prep(
    const float* __restrict__ W, const int* __restrict__ idx,
    unsigned short* __restrict__ Wt, int* __restrict__ cnt,
    int* __restrict__ base8, int* __restrict__ rows) {
  const int bid = blockIdx.x;
  const int t = threadIdx.x;

  if (bid >= 2048) {
    __shared__ int sc[256][8];
    int myi[16];
#pragma unroll
    for (int i = 0; i < 4; ++i) {
      const int4 v = *(const int4*)(idx + t * 16 + i * 4);
      myi[i * 4 + 0] = v.x; myi[i * 4 + 1] = v.y;
      myi[i * 4 + 2] = v.z; myi[i * 4 + 3] = v.w;
    }
    int c[8];
#pragma unroll
    for (int h = 0; h < 8; ++h) c[h] = 0;
#pragma unroll
    for (int e = 0; e < 16; ++e)
#pragma unroll
      for (int h = 0; h < 8; ++h) c[h] += (myi[e] == h) ? 1 : 0;

    int val[8];
#pragma unroll
    for (int h = 0; h < 8; ++h) { val[h] = c[h]; sc[t][h] = c[h]; }
    __syncthreads();
    for (int off = 1; off < 256; off <<= 1) {
      int nb[8];
#pragma unroll
      for (int h = 0; h < 8; ++h) nb[h] = (t >= off) ? sc[t - off][h] : 0;
      __syncthreads();
#pragma unroll
      for (int h = 0; h < 8; ++h) { val[h] += nb[h]; sc[t][h] = val[h]; }
      __syncthreads();
    }
    int tot[8], excl[8];
#pragma unroll
    for (int h = 0; h < 8; ++h) tot[h] = sc[255][h];
#pragma unroll
    for (int h = 0; h < 8; ++h) excl[h] = val[h] - c[h];
    int bases[9];
    bases[0] = 0;
#pragma unroll
    for (int h = 0; h < 7; ++h) bases[h + 1] = (bases[h] + tot[h] + 7) & ~7;
    bases[8] = bases[7] + tot[7];
#pragma unroll
    for (int h = 0; h < 8; ++h) {
      int pos = bases[h] + excl[h];
#pragma unroll
      for (int e = 0; e < 16; ++e) {
        if (myi[e] == h) { rows[pos] = t * 16 + e; ++pos; }
      }
    }
    if (t < 56) {
      const int hh = t >> 3, j = t & 7;
      const int pos = bases[hh] + tot[hh] + j;
      if (pos < bases[hh + 1]) rows[pos] = 0;
    }
    if (t < 128) {
      const int pos = bases[8] + t;
      if (pos < 4160) rows[pos] = 0;
    }
    if (t < 8) cnt[t] = tot[t];
    if (t == 0) {
#pragma unroll
      for (int h = 0; h < 9; ++h) base8[h] = bases[h];
    }
    return;
  }

  // ---- transpose block: 64x64 tile of head h ----
  __shared__ unsigned short tile[64][68];
  const int h = bid >> 8;
  const int rem = bid & 255;
  const int d0 = (rem >> 4) << 6;
  const int f0 = (rem & 15) << 6;
  const int c4 = (t & 15) * 4;
  const int r0 = t >> 4;
#pragma unroll
  for (int i = 0; i < 4; ++i) {
    const int r = r0 + i * 16;
    const float4 v = *(const float4*)(W + (size_t)(h * 1024 + d0 + r) * 1024 + f0 + c4);
    tile[r][c4 + 0] = f2bf(v.x);
    tile[r][c4 + 1] = f2bf(v.y);
    tile[r][c4 + 2] = f2bf(v.z);
    tile[r][c4 + 3] = f2bf(v.w);
  }
  __syncthreads();
#pragma unroll
  for (int i = 0; i < 4; ++i) {
    const int fr = r0 + i * 16;
    ushort4 o;
    o.x = tile[c4 + 0][fr];
    o.y = tile[c4 + 1][fr];
    o.z = tile[c4 + 2][fr];
    o.w = tile[c4 + 3][fr];
    *(ushort4*)(Wt + (size_t)(h * 1024 + f0 + fr) * 1024 + d0 + c4) = o;
  }
}

// Kernel 2: plain gather-copy X row rows[slot] -> Ap[slot] bf16.
__global__ __launch_bounds__(256) void k_gather(
    const float* __restrict__ X, const int* __restrict__ rows,
    unsigned short* __restrict__ Ap) {
  const int slot = blockIdx.x;
  const int b = rows[slot];
  const int t = threadIdx.x;
  const float4 v = *(const float4*)(X + (size_t)b * 1024 + t * 4);
  ushort4 o;
  o.x = f2bf(v.x); o.y = f2bf(v.y); o.z = f2bf(v.z); o.w = f2bf(v.w);
  *(ushort4*)(Ap + (size_t)slot * 1024 + t * 4) = o;
}

// Kernel 3: grouped GEMM. 64x64 tile, BK=128, full K (8 steps). 4 waves
// (2x2, each 32x32, 2x2 frag accs). SINGLE 32KB LDS buffer; staging =
// global->reg (plain layout) then swizzled ds_write (chunk ^= row&7 within
// each 256B row). 1024 working blocks -> 4 resident/CU (LDS cap 5, VGPR<=128)
// = 16 waves/CU = 4 independent step-streams. Plain-store epilogue + bias.
// h=blk&7 -> XCD L2 affinity for the head's Wt/Ap panels.
__global__ __launch_bounds__(256, 4) void k_gemm(
    const unsigned short* __restrict__ Ap, const unsigned short* __restrict__ Wt,
    const int* __restrict__ rows, const int* __restrict__ cnt,
    const int* __restrict__ base8,
    const float* __restrict__ bias, float* __restrict__ out) {
  __shared__ __align__(16) unsigned short As[64 * 128];  // 16KB
  __shared__ __align__(16) unsigned short Bs[64 * 128];  // 16KB

  const int blk = blockIdx.x;
  const int h = blk & 7;           // head -> XCD affinity
  const int nt = (blk >> 3) & 15;  // 16 n-tiles of 64
  const int mt = blk >> 7;         // up to 10 m-tiles of 64

  const int cnt_h = cnt[h];
  const int basep = base8[h];
  const int m0 = mt * 64;
  if (m0 >= cnt_h) return;
  const int n0 = nt * 64;

  const int t = threadIdx.x;
  const int lane = t & 63;
  const int wave = t >> 6;
  const int wr = wave >> 1, wc = wave & 1;  // wave tile: 32x32

  // ---- staging addressing: thread t owns row t>>2 (0..63), chunks (t&3)+4i
  const int srow = t >> 2;
  const int c0 = t & 3;
  int arow = basep + m0 + srow;
  arow = arow < 4159 ? arow : 4159;  // clamp into Ap's 4160 rows
  const char* aSrc = (const char*)Ap + (size_t)arow * 2048;
  const char* bSrc = (const char*)Wt + (size_t)(h * 1024 + n0 + srow) * 2048;
  int wOff[4];  // swizzled LDS byte offsets (same for A and B: same row map)
#pragma unroll
  for (int i = 0; i < 4; ++i) {
    const int ci = c0 + 4 * i;
    wOff[i] = srow * 256 + ((ci ^ (srow & 7)) << 4);
  }

  uint4 sa[4], sb[4];
  auto load = [&](int kt) {
    const int kb = kt * 256;  // byte offset of K-tile
#pragma unroll
    for (int i = 0; i < 4; ++i) {
      sa[i] = *(const uint4*)(aSrc + kb + (c0 + 4 * i) * 16);
      sb[i] = *(const uint4*)(bSrc + kb + (c0 + 4 * i) * 16);
    }
  };
  auto store = [&]() {
#pragma unroll
    for (int i = 0; i < 4; ++i) {
      *(uint4*)((char*)As + wOff[i]) = sa[i];
      *(uint4*)((char*)Bs + wOff[i]) = sb[i];
    }
  };

  // ---- frag read addressing: row*256 + ((ksub<<2) ^ q)<<4, q = kg ^ (row&7)
  const int kg = lane >> 4;
  const int rA = wr * 32 + (lane & 15);  // base row of A frags (m=0)
  const int rB = wc * 32 + (lane & 15);

  f32x4 acc[2][2];
#pragma unroll
  for (int m = 0; m < 2; ++m)
#pragma unroll
    for (int n = 0; n < 2; ++n)
      acc[m][n] = (f32x4){0.f, 0.f, 0.f, 0.f};

  auto compute = [&]() {
#pragma unroll
    for (int ksub = 0; ksub < 4; ++ksub) {
      bf16x8 af[2], bfr[2];
#pragma unroll
      for (int m = 0; m < 2; ++m) {
        const int row = rA + m * 16;
        const int q = kg ^ (row & 7);
        af[m] = *(const bf16x8*)((const char*)As + row * 256 + (((ksub << 2) ^ q) << 4));
      }
#pragma unroll
      for (int n = 0; n < 2; ++n) {
        const int row = rB + n * 16;
        const int q = kg ^ (row & 7);
        bfr[n] = *(const bf16x8*)((const char*)Bs + row * 256 + (((ksub << 2) ^ q) << 4));
      }
#pragma unroll
      for (int m = 0; m < 2; ++m)
#pragma unroll
        for (int n = 0; n < 2; ++n)
          acc[m][n] = __builtin_amdgcn_mfma_f32_16x16x32_bf16(af[m], bfr[n], acc[m][n], 0, 0, 0);
    }
  };

  load(0);
  for (int kt = 0; kt < 8; ++kt) {
    __syncthreads();      // previous step's readers done with LDS
    store();              // compiler waits vmcnt for sa/sb automatically
    __syncthreads();      // LDS tile ready
    if (kt < 7) load(kt + 1);  // next tile -> regs, hidden under compute
    compute();
  }

  // ---- epilogue: plain scatter through rows[] + bias
  int rmap[2][4];
  bool vld[2][4];
#pragma unroll
  for (int m = 0; m < 2; ++m) {
#pragma unroll
    for (int j = 0; j < 4; ++j) {
      const int lr = wr * 32 + m * 16 + (lane >> 4) * 4 + j;
      const bool v = (m0 + lr) < cnt_h;
      vld[m][j] = v;
      rmap[m][j] = v ? rows[basep + m0 + lr] : 0;
    }
  }
#pragma unroll
  for (int n = 0; n < 2; ++n) {
    const int c = n0 + wc * 32 + n * 16 + (lane & 15);
    const float bv = bias[h * 1024 + c];
#pragma unroll
    for (int m = 0; m < 2; ++m) {
#pragma unroll
      for (int j = 0; j < 4; ++j) {
        if (vld[m][j])
          out[(size_t)rmap[m][j] * 1024 + c] = acc[m][n][j] + bv;
      }
    }
  }
}

extern "C" void kernel_launch(void* const* d_in, const int* in_sizes, int n_in,
                              void* d_out, int out_size, void* d_ws, size_t ws_size,
                              hipStream_t stream) {
  const float* X = (const float*)d_in[0];
  const int* idx = (const int*)d_in[1];
  const float* W = (const float*)d_in[2];
  const float* bias = (const float*)d_in[3];
  float* out = (float*)d_out;

  char* ws = (char*)d_ws;
  int* cnt = (int*)ws;                                   // 8 ints @ 0
  int* base8 = (int*)(ws + 64);                          // 9 ints @ 64
  int* rows = (int*)(ws + 256);                          // 4160 ints
  unsigned short* Wt = (unsigned short*)(ws + 32768);    // 8M bf16 = 16 MB
  unsigned short* Ap = (unsigned short*)(ws + 32768 + 16777216);  // 4160 rows * 2KB

  k_prep<<<dim3(2049), 256, 0, stream>>>(W, idx, Wt, cnt, base8, rows);
  k_gather<<<dim3(4160), 256, 0, stream>>>(X, rows, Ap);
  // 8 heads (xcd-affine) x 16 nt x 10 mt (early-return past cnt_h)
  k_gemm<<<dim3(8 * 16 * 10), 256, 0, stream>>>(Ap, Wt, rows, cnt, base8, bias, out);
}

// Round 11
// 53.095 us; speedup vs baseline: 2.2458x; 2.2458x over previous
//
#include <hip/hip_runtime.h>

// MultiHeadDense: out[b] = x[b] @ W[idx[b]] + bias[idx[b]]
// B=4096, D=1024, F=1024, H=8. fp32 in/out; bf16 MFMA internally.
// Round 11: r10 structure (64x64 tile, BK=128, single 32KB LDS buffer,
// reg-bounce staging, 4 resident blocks/CU, full-K no atomics) with the
// scratch-spill fixed: ALL staged data in NAMED scalars (no arrays, no
// lambdas) so nothing can be demoted to scratch (r10: VGPR=44 + 224MB
// spill writes). Contiguous-64B per-thread global loads; 2-way-max LDS
// conflicts on write and read via chunk^row XOR swizzle.

typedef __attribute__((ext_vector_type(8))) short bf16x8;
typedef __attribute__((ext_vector_type(4))) float f32x4;

static __device__ __forceinline__ unsigned short f2bf(float f) {
  union { float f; unsigned int u; } c; c.f = f;
  unsigned int u = c.u;
  return (unsigned short)((u + 0x7fffu + ((u >> 16) & 1u)) >> 16);
}

// Kernel 1 (fused): blocks 0..2047 transpose+convert W [H][D][F] fp32 ->
// Wt [H][F][D] bf16 (plain row-major). Block 2048: counting-sort scan of
// idx -> rows[] + cnt[] + base8[] (8-aligned head bases; gaps zero-filled).
__global__ __launch_bounds__(256) void k_prep(
    const float* __restrict__ W, const int* __restrict__ idx,
    unsigned short* __restrict__ Wt, int* __restrict__ cnt,
    int* __restrict__ base8, int* __restrict__ rows) {
  const int bid = blockIdx.x;
  const int t = threadIdx.x;

  if (bid >= 2048) {
    __shared__ int sc[256][8];
    int myi[16];
#pragma unroll
    for (int i = 0; i < 4; ++i) {
      const int4 v = *(const int4*)(idx + t * 16 + i * 4);
      myi[i * 4 + 0] = v.x; myi[i * 4 + 1] = v.y;
      myi[i * 4 + 2] = v.z; myi[i * 4 + 3] = v.w;
    }
    int c[8];
#pragma unroll
    for (int h = 0; h < 8; ++h) c[h] = 0;
#pragma unroll
    for (int e = 0; e < 16; ++e)
#pragma unroll
      for (int h = 0; h < 8; ++h) c[h] += (myi[e] == h) ? 1 : 0;

    int val[8];
#pragma unroll
    for (int h = 0; h < 8; ++h) { val[h] = c[h]; sc[t][h] = c[h]; }
    __syncthreads();
    for (int off = 1; off < 256; off <<= 1) {
      int nb[8];
#pragma unroll
      for (int h = 0; h < 8; ++h) nb[h] = (t >= off) ? sc[t - off][h] : 0;
      __syncthreads();
#pragma unroll
      for (int h = 0; h < 8; ++h) { val[h] += nb[h]; sc[t][h] = val[h]; }
      __syncthreads();
    }
    int tot[8], excl[8];
#pragma unroll
    for (int h = 0; h < 8; ++h) tot[h] = sc[255][h];
#pragma unroll
    for (int h = 0; h < 8; ++h) excl[h] = val[h] - c[h];
    int bases[9];
    bases[0] = 0;
#pragma unroll
    for (int h = 0; h < 7; ++h) bases[h + 1] = (bases[h] + tot[h] + 7) & ~7;
    bases[8] = bases[7] + tot[7];
#pragma unroll
    for (int h = 0; h < 8; ++h) {
      int pos = bases[h] + excl[h];
#pragma unroll
      for (int e = 0; e < 16; ++e) {
        if (myi[e] == h) { rows[pos] = t * 16 + e; ++pos; }
      }
    }
    if (t < 56) {
      const int hh = t >> 3, j = t & 7;
      const int pos = bases[hh] + tot[hh] + j;
      if (pos < bases[hh + 1]) rows[pos] = 0;
    }
    if (t < 128) {
      const int pos = bases[8] + t;
      if (pos < 4160) rows[pos] = 0;
    }
    if (t < 8) cnt[t] = tot[t];
    if (t == 0) {
#pragma unroll
      for (int h = 0; h < 9; ++h) base8[h] = bases[h];
    }
    return;
  }

  // ---- transpose block: 64x64 tile of head h ----
  __shared__ unsigned short tile[64][68];
  const int h = bid >> 8;
  const int rem = bid & 255;
  const int d0 = (rem >> 4) << 6;
  const int f0 = (rem & 15) << 6;
  const int c4 = (t & 15) * 4;
  const int r0 = t >> 4;
#pragma unroll
  for (int i = 0; i < 4; ++i) {
    const int r = r0 + i * 16;
    const float4 v = *(const float4*)(W + (size_t)(h * 1024 + d0 + r) * 1024 + f0 + c4);
    tile[r][c4 + 0] = f2bf(v.x);
    tile[r][c4 + 1] = f2bf(v.y);
    tile[r][c4 + 2] = f2bf(v.z);
    tile[r][c4 + 3] = f2bf(v.w);
  }
  __syncthreads();
#pragma unroll
  for (int i = 0; i < 4; ++i) {
    const int fr = r0 + i * 16;
    ushort4 o;
    o.x = tile[c4 + 0][fr];
    o.y = tile[c4 + 1][fr];
    o.z = tile[c4 + 2][fr];
    o.w = tile[c4 + 3][fr];
    *(ushort4*)(Wt + (size_t)(h * 1024 + f0 + fr) * 1024 + d0 + c4) = o;
  }
}

// Kernel 2: plain gather-copy X row rows[slot] -> Ap[slot] bf16.
__global__ __launch_bounds__(256) void k_gather(
    const float* __restrict__ X, const int* __restrict__ rows,
    unsigned short* __restrict__ Ap) {
  const int slot = blockIdx.x;
  const int b = rows[slot];
  const int t = threadIdx.x;
  const float4 v = *(const float4*)(X + (size_t)b * 1024 + t * 4);
  ushort4 o;
  o.x = f2bf(v.x); o.y = f2bf(v.y); o.z = f2bf(v.z); o.w = f2bf(v.w);
  *(ushort4*)(Ap + (size_t)slot * 1024 + t * 4) = o;
}

// Kernel 3: grouped GEMM. 64x64 tile, BK=128, full K (8 steps). 4 waves
// (2x2, each 32x32). Single 32KB LDS buffer; staging = global->NAMED regs
// -> swizzled ds_write (logical chunk c of row r stored at c^(r&7)).
// ~1100 working blocks -> 4 resident/CU (VGPR<=128, LDS cap 5) = 16
// waves/CU = 4 independent step-streams. Plain-store epilogue + bias.
// h=blk&7 -> XCD L2 affinity for the head's Wt/Ap panels.
__global__ __launch_bounds__(256, 4) void k_gemm(
    const unsigned short* __restrict__ Ap, const unsigned short* __restrict__ Wt,
    const int* __restrict__ rows, const int* __restrict__ cnt,
    const int* __restrict__ base8,
    const float* __restrict__ bias, float* __restrict__ out) {
  __shared__ __align__(16) unsigned short As[64 * 128];  // 16KB
  __shared__ __align__(16) unsigned short Bs[64 * 128];  // 16KB

  const int blk = blockIdx.x;
  const int h = blk & 7;           // head -> XCD affinity
  const int nt = (blk >> 3) & 15;  // 16 n-tiles of 64
  const int mt = blk >> 7;         // up to 12 m-tiles of 64

  const int cnt_h = cnt[h];
  const int basep = base8[h];
  const int m0 = mt * 64;
  if (m0 >= cnt_h) return;
  const int n0 = nt * 64;

  const int t = threadIdx.x;
  const int lane = t & 63;
  const int wave = t >> 6;
  const int wr = wave >> 1, wc = wave & 1;  // wave tile: 32x32

  // staging: thread t owns row t>>2 (0..63), logical chunks c0..c0+3 (64B).
  const int srow = t >> 2;
  const int c0 = (t & 3) << 2;
  int arow = basep + m0 + srow;
  arow = arow < 4159 ? arow : 4159;  // clamp into Ap's 4160 rows
  const char* aSrc = (const char*)Ap + (size_t)arow * 2048 + c0 * 16;
  const char* bSrc = (const char*)Wt + (size_t)(h * 1024 + n0 + srow) * 2048 + c0 * 16;

  const int r7 = srow & 7;
  const int wbase = srow * 256;
  const int w0 = wbase + (((c0 + 0) ^ r7) << 4);
  const int w1 = wbase + (((c0 + 1) ^ r7) << 4);
  const int w2 = wbase + (((c0 + 2) ^ r7) << 4);
  const int w3 = wbase + (((c0 + 3) ^ r7) << 4);

  uint4 a0, a1, a2, a3, b0, b1, b2, b3;  // named -> guaranteed VGPRs

#define LOADREG(kt) do {                                        \
    const char* ap_ = aSrc + (kt) * 256;                        \
    const char* bp_ = bSrc + (kt) * 256;                        \
    a0 = *(const uint4*)(ap_);                                  \
    a1 = *(const uint4*)(ap_ + 16);                             \
    a2 = *(const uint4*)(ap_ + 32);                             \
    a3 = *(const uint4*)(ap_ + 48);                             \
    b0 = *(const uint4*)(bp_);                                  \
    b1 = *(const uint4*)(bp_ + 16);                             \
    b2 = *(const uint4*)(bp_ + 32);                             \
    b3 = *(const uint4*)(bp_ + 48);                             \
  } while (0)

#define STORELDS() do {                                         \
    *(uint4*)((char*)As + w0) = a0;                             \
    *(uint4*)((char*)As + w1) = a1;                             \
    *(uint4*)((char*)As + w2) = a2;                             \
    *(uint4*)((char*)As + w3) = a3;                             \
    *(uint4*)((char*)Bs + w0) = b0;                             \
    *(uint4*)((char*)Bs + w1) = b1;                             \
    *(uint4*)((char*)Bs + w2) = b2;                             \
    *(uint4*)((char*)Bs + w3) = b3;                             \
  } while (0)

  const int kg = lane >> 4;
  const int rA = wr * 32 + (lane & 15);
  const int rB = wc * 32 + (lane & 15);
  const int rA7 = rA & 7;  // rows rA and rA+16 share &7
  const int rB7 = rB & 7;

  f32x4 acc00 = {0.f, 0.f, 0.f, 0.f}, acc01 = {0.f, 0.f, 0.f, 0.f};
  f32x4 acc10 = {0.f, 0.f, 0.f, 0.f}, acc11 = {0.f, 0.f, 0.f, 0.f};

#define COMPUTE() do {                                                         \
    _Pragma("unroll")                                                          \
    for (int ksub = 0; ksub < 4; ++ksub) {                                     \
      const int xa = ((((ksub << 2) | kg) ^ rA7) << 4);                        \
      const int xb = ((((ksub << 2) | kg) ^ rB7) << 4);                        \
      bf16x8 af0 = *(const bf16x8*)((const char*)As + rA * 256 + xa);          \
      bf16x8 af1 = *(const bf16x8*)((const char*)As + (rA + 16) * 256 + xa);   \
      bf16x8 bf0 = *(const bf16x8*)((const char*)Bs + rB * 256 + xb);          \
      bf16x8 bf1 = *(const bf16x8*)((const char*)Bs + (rB + 16) * 256 + xb);   \
      acc00 = __builtin_amdgcn_mfma_f32_16x16x32_bf16(af0, bf0, acc00, 0, 0, 0); \
      acc01 = __builtin_amdgcn_mfma_f32_16x16x32_bf16(af0, bf1, acc01, 0, 0, 0); \
      acc10 = __builtin_amdgcn_mfma_f32_16x16x32_bf16(af1, bf0, acc10, 0, 0, 0); \
      acc11 = __builtin_amdgcn_mfma_f32_16x16x32_bf16(af1, bf1, acc11, 0, 0, 0); \
    }                                                                          \
  } while (0)

  LOADREG(0);
  for (int kt = 0; kt < 8; ++kt) {
    __syncthreads();           // prev step's readers done with the buffer
    STORELDS();                // compiler inserts vmcnt waits for a*/b*
    __syncthreads();           // tile visible to all waves
    if (kt < 7) LOADREG(kt + 1);  // next tile -> regs, hides under compute
    COMPUTE();
  }

  // ---- epilogue: plain scatter through rows[] + bias
  const int jrow = (lane >> 4) * 4;
  const int ccol = lane & 15;
#pragma unroll
  for (int m = 0; m < 2; ++m) {
#pragma unroll
    for (int j = 0; j < 4; ++j) {
      const int lr = wr * 32 + m * 16 + jrow + j;
      if (m0 + lr < cnt_h) {
        const int b = rows[basep + m0 + lr];
#pragma unroll
        for (int n = 0; n < 2; ++n) {
          const int c = n0 + wc * 32 + n * 16 + ccol;
          float v;
          if (m == 0 && n == 0) v = acc00[j];
          else if (m == 0 && n == 1) v = acc01[j];
          else if (m == 1 && n == 0) v = acc10[j];
          else v = acc11[j];
          out[(size_t)b * 1024 + c] = v + bias[h * 1024 + c];
        }
      }
    }
  }
}

extern "C" void kernel_launch(void* const* d_in, const int* in_sizes, int n_in,
                              void* d_out, int out_size, void* d_ws, size_t ws_size,
                              hipStream_t stream) {
  const float* X = (const float*)d_in[0];
  const int* idx = (const int*)d_in[1];
  const float* W = (const float*)d_in[2];
  const float* bias = (const float*)d_in[3];
  float* out = (float*)d_out;

  char* ws = (char*)d_ws;
  int* cnt = (int*)ws;                                   // 8 ints @ 0
  int* base8 = (int*)(ws + 64);                          // 9 ints @ 64
  int* rows = (int*)(ws + 256);                          // 4160 ints
  unsigned short* Wt = (unsigned short*)(ws + 32768);    // 8M bf16 = 16 MB
  unsigned short* Ap = (unsigned short*)(ws + 32768 + 16777216);  // 4160 rows * 2KB

  k_prep<<<dim3(2049), 256, 0, stream>>>(W, idx, Wt, cnt, base8, rows);
  k_gather<<<dim3(4160), 256, 0, stream>>>(X, rows, Ap);
  // 8 heads (xcd-affine) x 16 nt x 12 mt (early-return past cnt_h)
  k_gemm<<<dim3(8 * 16 * 12), 256, 0, stream>>>(Ap, Wt, rows, cnt, base8, bias, out);
}

// Round 12
// 48.903 us; speedup vs baseline: 2.4383x; 1.0857x over previous
//
#include <hip/hip_runtime.h>

// MultiHeadDense: out[b] = x[b] @ W[idx[b]] + bias[idx[b]]
// B=4096, D=1024, F=1024, H=8. fp32 in/out; bf16 MFMA internally.
// Round 12: r6 (best, gemm~29us) + ring-3 LDS schedule:
//  - 64x64 tile, BK=64, 16 steps, 1024 working blocks -> 3 resident/CU
//    (48KB LDS cap) = 12 waves/CU.
//  - ONE barrier per step (ring-3: stage target's readers finished at ts-1,
//    separated by this step's barrier) vs r6's two.
//  - stage issued BEFORE compute -> ~2 steps of load lead time.
//  - counted vmcnt(4), never 0 mid-loop (T4).
// Staging sources LINEAR (LDS XOR swizzle baked into Ap/Wt by prep/gather).

typedef __attribute__((ext_vector_type(8))) short bf16x8;
typedef __attribute__((ext_vector_type(4))) float f32x4;

#define WAITV(N) asm volatile("s_waitcnt vmcnt(" #N ")" ::: "memory")

static __device__ __forceinline__ unsigned short f2bf(float f) {
  union { float f; unsigned int u; } c; c.f = f;
  unsigned int u = c.u;
  return (unsigned short)((u + 0x7fffu + ((u >> 16) & 1u)) >> 16);
}

static __device__ __forceinline__ void gload16(const void* g, void* s) {
  __builtin_amdgcn_global_load_lds(
      (const __attribute__((address_space(1))) void*)g,
      (__attribute__((address_space(3))) void*)s, 16, 0, 0);
}

// Kernel 1 (fused): blocks 0..2047 transpose+convert W [H][D][F] fp32 ->
// Wt [H][F][D-swizzled] bf16 (chunk c of each 64-K group stored at c^(frow&7)).
// Block 2048: counting-sort scan of idx -> rows[] + cnt[] + base8[].
__global__ __launch_bounds__(256) void k_prep(
    const float* __restrict__ W, const int* __restrict__ idx,
    unsigned short* __restrict__ Wt, int* __restrict__ cnt,
    int* __restrict__ base8, int* __restrict__ rows) {
  const int bid = blockIdx.x;
  const int t = threadIdx.x;

  if (bid >= 2048) {
    __shared__ int sc[256][8];
    int myi[16];
#pragma unroll
    for (int i = 0; i < 4; ++i) {
      const int4 v = *(const int4*)(idx + t * 16 + i * 4);
      myi[i * 4 + 0] = v.x; myi[i * 4 + 1] = v.y;
      myi[i * 4 + 2] = v.z; myi[i * 4 + 3] = v.w;
    }
    int c[8];
#pragma unroll
    for (int h = 0; h < 8; ++h) c[h] = 0;
#pragma unroll
    for (int e = 0; e < 16; ++e)
#pragma unroll
      for (int h = 0; h < 8; ++h) c[h] += (myi[e] == h) ? 1 : 0;

    int val[8];
#pragma unroll
    for (int h = 0; h < 8; ++h) { val[h] = c[h]; sc[t][h] = c[h]; }
    __syncthreads();
    for (int off = 1; off < 256; off <<= 1) {
      int nb[8];
#pragma unroll
      for (int h = 0; h < 8; ++h) nb[h] = (t >= off) ? sc[t - off][h] : 0;
      __syncthreads();
#pragma unroll
      for (int h = 0; h < 8; ++h) { val[h] += nb[h]; sc[t][h] = val[h]; }
      __syncthreads();
    }
    int tot[8], excl[8];
#pragma unroll
    for (int h = 0; h < 8; ++h) tot[h] = sc[255][h];
#pragma unroll
    for (int h = 0; h < 8; ++h) excl[h] = val[h] - c[h];
    int bases[9];
    bases[0] = 0;
#pragma unroll
    for (int h = 0; h < 7; ++h) bases[h + 1] = (bases[h] + tot[h] + 7) & ~7;
    bases[8] = bases[7] + tot[7];
#pragma unroll
    for (int h = 0; h < 8; ++h) {
      int pos = bases[h] + excl[h];
#pragma unroll
      for (int e = 0; e < 16; ++e) {
        if (myi[e] == h) { rows[pos] = t * 16 + e; ++pos; }
      }
    }
    if (t < 56) {
      const int hh = t >> 3, j = t & 7;
      const int pos = bases[hh] + tot[hh] + j;
      if (pos < bases[hh + 1]) rows[pos] = 0;
    }
    if (t < 128) {
      const int pos = bases[8] + t;
      if (pos < 4160) rows[pos] = 0;
    }
    if (t < 8) cnt[t] = tot[t];
    if (t == 0) {
#pragma unroll
      for (int h = 0; h < 9; ++h) base8[h] = bases[h];
    }
    return;
  }

  // ---- transpose block: 64x64 tile of head h ----
  __shared__ unsigned short tile[64][68];
  const int h = bid >> 8;
  const int rem = bid & 255;
  const int d0 = (rem >> 4) << 6;
  const int f0 = (rem & 15) << 6;
  const int c4 = (t & 15) * 4;
  const int r0 = t >> 4;
#pragma unroll
  for (int i = 0; i < 4; ++i) {
    const int r = r0 + i * 16;
    const float4 v = *(const float4*)(W + (size_t)(h * 1024 + d0 + r) * 1024 + f0 + c4);
    tile[r][c4 + 0] = f2bf(v.x);
    tile[r][c4 + 1] = f2bf(v.y);
    tile[r][c4 + 2] = f2bf(v.z);
    tile[r][c4 + 3] = f2bf(v.w);
  }
  __syncthreads();
  const int chunk = c4 >> 3;
  const int half = (c4 >> 2) & 1;
#pragma unroll
  for (int i = 0; i < 4; ++i) {
    const int fr = r0 + i * 16;
    const int frow = f0 + fr;
    ushort4 o;
    o.x = tile[c4 + 0][fr];
    o.y = tile[c4 + 1][fr];
    o.z = tile[c4 + 2][fr];
    o.w = tile[c4 + 3][fr];
    const int cS = chunk ^ (frow & 7);  // baked LDS swizzle
    *(ushort4*)((char*)Wt + (size_t)(h * 1024 + frow) * 2048 +
                (d0 << 1) + (cS << 4) + (half << 3)) = o;
  }
}

// Kernel 2: permuted gather-copy X row rows[slot] -> Ap[slot] (bf16,
// chunk-swizzled by slot&7 to match the LDS XOR on read).
__global__ __launch_bounds__(256) void k_gather(
    const float* __restrict__ X, const int* __restrict__ rows,
    unsigned short* __restrict__ Ap) {
  const int slot = blockIdx.x;
  const int b = rows[slot];
  const int t = threadIdx.x;
  const float4 v = *(const float4*)(X + (size_t)b * 1024 + t * 4);
  ushort4 o;
  o.x = f2bf(v.x); o.y = f2bf(v.y); o.z = f2bf(v.z); o.w = f2bf(v.w);
  const int g = t >> 4;
  const int cS = ((t >> 1) & 7) ^ (slot & 7);
  *(ushort4*)((char*)Ap + (size_t)slot * 2048 + (g << 7) + (cS << 4) +
              ((t & 1) << 3)) = o;
}

// Kernel 3: grouped GEMM, 64x64 tile, BK=64, 16 steps, 4 waves (2x2, each
// 32x32, 2x2 frag accs). Ring-3 LDS (48KB -> 3 resident blocks/CU), ONE
// barrier/step, counted vmcnt(4), stage issued 2 steps ahead of use.
// Linear staging sources (swizzle baked in Ap/Wt); XOR on ds_read.
// h=blk&7 -> XCD L2 affinity. Plain-store epilogue + bias.
__global__ __launch_bounds__(256) void k_gemm(
    const unsigned short* __restrict__ Ap, const unsigned short* __restrict__ Wt,
    const int* __restrict__ rows, const int* __restrict__ cnt,
    const int* __restrict__ base8,
    const float* __restrict__ bias, float* __restrict__ out) {
  __shared__ __align__(16) unsigned short As[3][64 * 64];  // 3 x 8KB
  __shared__ __align__(16) unsigned short Bs[3][64 * 64];  // 3 x 8KB

  const int blk = blockIdx.x;
  const int h = blk & 7;           // head -> XCD affinity
  const int nt = (blk >> 3) & 15;  // 16 n-tiles of 64
  const int mt = blk >> 7;         // up to 16 m-tiles of 64

  const int cnt_h = cnt[h];
  const int basep = base8[h];
  const int m0 = mt * 64;
  if (m0 >= cnt_h) return;
  const int n0 = nt * 64;

  const int t = threadIdx.x;
  const int lane = t & 63;
  const int wave = t >> 6;
  const int wr = wave >> 1, wc = wave & 1;  // wave tile: 32x32

  // staging: each gload16 instr covers 32 rows (256 thr x 16B); 2 for A, 2 for B
  const int srow = t >> 3;                 // 0..31
  const int scol = (t & 7) << 4;           // linear 16B chunk (swizzle baked)
  int ar0 = basep + m0 + srow;      ar0 = ar0 < 4159 ? ar0 : 4159;
  int ar1 = basep + m0 + 32 + srow; ar1 = ar1 < 4159 ? ar1 : 4159;
  const char* aRow0 = (const char*)Ap + (size_t)ar0 * 2048 + scol;
  const char* aRow1 = (const char*)Ap + (size_t)ar1 * 2048 + scol;
  const char* bRow0 = (const char*)Wt + (size_t)(h * 1024 + n0 + srow) * 2048 + scol;
  const char* bRow1 = (const char*)Wt + (size_t)(h * 1024 + n0 + 32 + srow) * 2048 + scol;

  f32x4 acc[2][2];
#pragma unroll
  for (int m = 0; m < 2; ++m)
#pragma unroll
    for (int n = 0; n < 2; ++n)
      acc[m][n] = (f32x4){0.f, 0.f, 0.f, 0.f};

  auto stage = [&](char* aDst, char* bDst, int k0) {  // 4 gload16 per thread
    const int kby = k0 * 2;
    gload16(aRow0 + kby, aDst + t * 16);
    gload16(aRow1 + kby, aDst + 4096 + t * 16);
    gload16(bRow0 + kby, bDst + t * 16);
    gload16(bRow1 + kby, bDst + 4096 + t * 16);
  };

  const int swz = (lane & 7) << 4;
  const int ra = (wr * 32 + (lane & 15)) * 128;  // A frag byte base (row*128B)
  const int rb = (wc * 32 + (lane & 15)) * 128;
  const int kc = (lane >> 4) << 4;

  auto compute = [&](const char* ab, const char* bb) {
#pragma unroll
    for (int ksub = 0; ksub < 2; ++ksub) {
      const int co = ((ksub * 64) + kc) ^ swz;
      const bf16x8 a0 = *(const bf16x8*)(ab + ra + co);
      const bf16x8 a1 = *(const bf16x8*)(ab + ra + 2048 + co);
      const bf16x8 b0 = *(const bf16x8*)(bb + rb + co);
      const bf16x8 b1 = *(const bf16x8*)(bb + rb + 2048 + co);
      acc[0][0] = __builtin_amdgcn_mfma_f32_16x16x32_bf16(a0, b0, acc[0][0], 0, 0, 0);
      acc[0][1] = __builtin_amdgcn_mfma_f32_16x16x32_bf16(a0, b1, acc[0][1], 0, 0, 0);
      acc[1][0] = __builtin_amdgcn_mfma_f32_16x16x32_bf16(a1, b0, acc[1][0], 0, 0, 0);
      acc[1][1] = __builtin_amdgcn_mfma_f32_16x16x32_bf16(a1, b1, acc[1][1], 0, 0, 0);
    }
  };

  // ring pointers: c0 = compute buf, c2 = stage target ((ts+2)%3)
  char* a0p = (char*)&As[0][0]; char* a1p = (char*)&As[1][0]; char* a2p = (char*)&As[2][0];
  char* b0p = (char*)&Bs[0][0]; char* b1p = (char*)&Bs[1][0]; char* b2p = (char*)&Bs[2][0];

  stage(a0p, b0p, 0);
  stage(a1p, b1p, 64);

  for (int ts = 0; ts < 15; ++ts) {
    WAITV(4);                          // stage ts landed; ts+1 stays in flight
    __builtin_amdgcn_s_barrier();
    __builtin_amdgcn_sched_barrier(0);
    if (ts < 14) stage(a2p, b2p, (ts + 2) * 64);  // readers done at ts-1
    __builtin_amdgcn_sched_barrier(0);
    compute(a0p, b0p);
    char* tA = a0p; a0p = a1p; a1p = a2p; a2p = tA;
    char* tB = b0p; b0p = b1p; b1p = b2p; b2p = tB;
  }
  WAITV(0);
  __builtin_amdgcn_s_barrier();
  __builtin_amdgcn_sched_barrier(0);
  compute(a0p, b0p);

  // ---- epilogue: plain scatter through rows[] + bias
  int rmap[2][4];
  bool vld[2][4];
#pragma unroll
  for (int m = 0; m < 2; ++m) {
#pragma unroll
    for (int j = 0; j < 4; ++j) {
      const int lr = wr * 32 + m * 16 + (lane >> 4) * 4 + j;
      const bool v = (m0 + lr) < cnt_h;
      vld[m][j] = v;
      rmap[m][j] = v ? rows[basep + m0 + lr] : 0;
    }
  }
#pragma unroll
  for (int n = 0; n < 2; ++n) {
    const int c = n0 + wc * 32 + n * 16 + (lane & 15);
    const float bv = bias[h * 1024 + c];
#pragma unroll
    for (int m = 0; m < 2; ++m) {
#pragma unroll
      for (int j = 0; j < 4; ++j) {
        if (vld[m][j])
          out[(size_t)rmap[m][j] * 1024 + c] = acc[m][n][j] + bv;
      }
    }
  }
}

extern "C" void kernel_launch(void* const* d_in, const int* in_sizes, int n_in,
                              void* d_out, int out_size, void* d_ws, size_t ws_size,
                              hipStream_t stream) {
  const float* X = (const float*)d_in[0];
  const int* idx = (const int*)d_in[1];
  const float* W = (const float*)d_in[2];
  const float* bias = (const float*)d_in[3];
  float* out = (float*)d_out;

  char* ws = (char*)d_ws;
  int* cnt = (int*)ws;                                   // 8 ints @ 0
  int* base8 = (int*)(ws + 64);                          // 9 ints @ 64
  int* rows = (int*)(ws + 256);                          // 4160 ints
  unsigned short* Wt = (unsigned short*)(ws + 32768);    // 8*1024 rows * 2KB = 16 MB
  unsigned short* Ap = (unsigned short*)(ws + 32768 + 16777216);  // 4160 rows * 2KB

  k_prep<<<dim3(2049), 256, 0, stream>>>(W, idx, Wt, cnt, base8, rows);
  k_gather<<<dim3(4160), 256, 0, stream>>>(X, rows, Ap);
  // 8 heads (xcd-affine) x 16 nt x 16 mt (early-return past cnt_h)
  k_gemm<<<dim3(8 * 16 * 16), 256, 0, stream>>>(Ap, Wt, rows, cnt, base8, bias, out);
}

// Round 13
// 47.354 us; speedup vs baseline: 2.5181x; 1.0327x over previous
//
#include <hip/hip_runtime.h>

// MultiHeadDense: out[b] = x[b] @ W[idx[b]] + bias[idx[b]]
// B=4096, D=1024, F=1024, H=8. fp32 in/out; bf16 MFMA internally.
// Round 13: dual-path staging. A via global_load_lds dbuf (26 GB/s/CU path,
// r12-proven addressing); B via direct vector loads to NAMED registers from
// fragment-packed Wt (r7-proven layout, ~29 GB/s/CU path). The two HW paths
// (LDS-DMA vs VMEM-return) should overlap -> ~2x staging rate.
// 64x64 tile, BK=64, 16 steps, full K (no atomics), 16KB LDS -> 4 resident
// blocks/CU. One barrier/step, counted vmcnt(4) (A-gloads older than B-loads
// in FIFO). Even/odd unroll keeps B register sets named (rule #20).

typedef __attribute__((ext_vector_type(8))) short bf16x8;
typedef __attribute__((ext_vector_type(4))) float f32x4;

#define WAITV(N) asm volatile("s_waitcnt vmcnt(" #N ")" ::: "memory")

static __device__ __forceinline__ unsigned short f2bf(float f) {
  union { float f; unsigned int u; } c; c.f = f;
  unsigned int u = c.u;
  return (unsigned short)((u + 0x7fffu + ((u >> 16) & 1u)) >> 16);
}

static __device__ __forceinline__ void gload16(const void* g, void* s) {
  __builtin_amdgcn_global_load_lds(
      (const __attribute__((address_space(1))) void*)g,
      (__attribute__((address_space(3))) void*)s, 16, 0, 0);
}

// Kernel 1 (fused, r7-verified): blocks 0..2047 transpose+convert W fp32 ->
// Wt fragment-packed [grp16][kc][kg][r][8]. Block 2048: counting-sort scan
// -> rows[] + cnt[] + base16[] (16-aligned head bases, gaps zero-filled).
__global__ __launch_bounds__(256) void k_prep(
    const float* __restrict__ W, const int* __restrict__ idx,
    unsigned short* __restrict__ Wt, int* __restrict__ cnt,
    int* __restrict__ base16, int* __restrict__ rows) {
  const int bid = blockIdx.x;
  const int t = threadIdx.x;

  if (bid >= 2048) {
    __shared__ int sc[256][8];
    int myi[16];
#pragma unroll
    for (int i = 0; i < 4; ++i) {
      const int4 v = *(const int4*)(idx + t * 16 + i * 4);
      myi[i * 4 + 0] = v.x; myi[i * 4 + 1] = v.y;
      myi[i * 4 + 2] = v.z; myi[i * 4 + 3] = v.w;
    }
    int c[8];
#pragma unroll
    for (int h = 0; h < 8; ++h) c[h] = 0;
#pragma unroll
    for (int e = 0; e < 16; ++e)
#pragma unroll
      for (int h = 0; h < 8; ++h) c[h] += (myi[e] == h) ? 1 : 0;

    int val[8];
#pragma unroll
    for (int h = 0; h < 8; ++h) { val[h] = c[h]; sc[t][h] = c[h]; }
    __syncthreads();
    for (int off = 1; off < 256; off <<= 1) {
      int nb[8];
#pragma unroll
      for (int h = 0; h < 8; ++h) nb[h] = (t >= off) ? sc[t - off][h] : 0;
      __syncthreads();
#pragma unroll
      for (int h = 0; h < 8; ++h) { val[h] += nb[h]; sc[t][h] = val[h]; }
      __syncthreads();
    }
    int tot[8], excl[8];
#pragma unroll
    for (int h = 0; h < 8; ++h) tot[h] = sc[255][h];
#pragma unroll
    for (int h = 0; h < 8; ++h) excl[h] = val[h] - c[h];
    int bases[9];
    bases[0] = 0;
#pragma unroll
    for (int h = 0; h < 7; ++h) bases[h + 1] = (bases[h] + tot[h] + 15) & ~15;
    bases[8] = bases[7] + tot[7];
#pragma unroll
    for (int h = 0; h < 8; ++h) {
      int pos = bases[h] + excl[h];
#pragma unroll
      for (int e = 0; e < 16; ++e) {
        if (myi[e] == h) { rows[pos] = t * 16 + e; ++pos; }
      }
    }
    if (t < 128) {
      const int hh = t >> 4, j = t & 15;
      const int pos = bases[hh] + tot[hh] + j;
      if (pos < bases[hh + 1]) rows[pos] = 0;
    }
    {
      const int pos = bases[8] + t;
      if (pos < 4352) rows[pos] = 0;
    }
    if (t < 8) cnt[t] = tot[t];
    if (t == 0) {
#pragma unroll
      for (int h = 0; h < 9; ++h) base16[h] = bases[h];
    }
    return;
  }

  // ---- transpose block: 64x64 tile of head h -> fragment-packed Wt ----
  __shared__ unsigned short tile[64][65];
  const int h = bid >> 8;
  const int rem = bid & 255;
  const int d0 = (rem >> 4) << 6;
  const int f0 = (rem & 15) << 6;
  {
    const int c4 = (t & 15) * 4;
    const int r0 = t >> 4;
#pragma unroll
    for (int i = 0; i < 4; ++i) {
      const int r = r0 + i * 16;
      const float4 v = *(const float4*)(W + (size_t)(h * 1024 + d0 + r) * 1024 + f0 + c4);
      tile[r][c4 + 0] = f2bf(v.x);
      tile[r][c4 + 1] = f2bf(v.y);
      tile[r][c4 + 2] = f2bf(v.z);
      tile[r][c4 + 3] = f2bf(v.w);
    }
  }
  __syncthreads();
  const int fgl = t >> 6;
  const int fr = t & 15;
  const int ksl = (t >> 4) & 3;
  const int frow = f0 + fgl * 16 + fr;
  const int fg = frow >> 4;
  const int kc = (d0 >> 5) + (ksl >> 1);
  const int kg0 = (ksl & 1) * 2;
  const size_t baseB = (((size_t)(h * 64 + fg) * 32) + kc) * 1024;  // bytes
#pragma unroll
  for (int q = 0; q < 4; ++q) {
    const int kg = kg0 + (q >> 1);
    const int e = (q & 1) * 4;
    const int dl = ksl * 16 + (q >> 1) * 8 + e;
    ushort4 o;
    o.x = tile[dl + 0][fgl * 16 + fr];
    o.y = tile[dl + 1][fgl * 16 + fr];
    o.z = tile[dl + 2][fgl * 16 + fr];
    o.w = tile[dl + 3][fgl * 16 + fr];
    *(ushort4*)((char*)Wt + baseB + kg * 256 + fr * 16 + e * 2) = o;
  }
}

// Kernel 2 (r6-verified bake): gather X row rows[slot] -> Ap[slot] bf16,
// chunk-swizzled by slot&7 (matches gemm's XOR ds_read).
__global__ __launch_bounds__(256) void k_gather(
    const float* __restrict__ X, const int* __restrict__ rows,
    unsigned short* __restrict__ Ap) {
  const int slot = blockIdx.x;
  const int b = rows[slot];
  const int t = threadIdx.x;
  const float4 v = *(const float4*)(X + (size_t)b * 1024 + t * 4);
  ushort4 o;
  o.x = f2bf(v.x); o.y = f2bf(v.y); o.z = f2bf(v.z); o.w = f2bf(v.w);
  const int g = t >> 4;
  const int cS = ((t >> 1) & 7) ^ (slot & 7);
  *(ushort4*)((char*)Ap + (size_t)slot * 2048 + (g << 7) + (cS << 4) +
              ((t & 1) << 3)) = o;
}

// Kernel 3: grouped GEMM, 64x64 tile, BK=64, 16 steps, full K.
// A: gload_lds dbuf (2x8KB), swizzle-baked Ap, XOR ds_read (r12 addressing).
// B: direct vector loads -> named regs from fragment-packed Wt (r7 layout).
// One barrier/step; WAITV(4): FIFO = [A(t+1) x2, B(t+1) x4], drains A(t+1).
// h=blk&7 -> XCD L2 affinity. Plain-store epilogue + bias.
__global__ __launch_bounds__(256) void k_gemm(
    const unsigned short* __restrict__ Ap, const unsigned short* __restrict__ Wt,
    const int* __restrict__ rows, const int* __restrict__ cnt,
    const int* __restrict__ base16,
    const float* __restrict__ bias, float* __restrict__ out) {
  __shared__ __align__(16) unsigned short As0[64 * 64];  // 8KB
  __shared__ __align__(16) unsigned short As1[64 * 64];  // 8KB

  const int blk = blockIdx.x;
  const int h = blk & 7;           // head -> XCD affinity
  const int nt = (blk >> 3) & 15;  // 16 n-tiles of 64
  const int mt = blk >> 7;         // up to 16 m-tiles of 64

  const int cnt_h = cnt[h];
  const int basep = base16[h];
  const int m0 = mt * 64;
  if (m0 >= cnt_h) return;
  const int n0 = nt * 64;

  const int t = threadIdx.x;
  const int lane = t & 63;
  const int wave = t >> 6;
  const int wr = wave >> 1, wc = wave & 1;  // wave tile: 32x32

  // ---- A staging (r12-proven): rows srow, srow+32; linear source (bake) ----
  const int srow = t >> 3;                 // 0..31
  const int scol = (t & 7) << 4;
  int ar0 = basep + m0 + srow;      ar0 = ar0 < 4351 ? ar0 : 4351;
  int ar1 = basep + m0 + 32 + srow; ar1 = ar1 < 4351 ? ar1 : 4351;
  const char* aRow0 = (const char*)Ap + (size_t)ar0 * 2048 + scol;
  const char* aRow1 = (const char*)Ap + (size_t)ar1 * 2048 + scol;

#define STAGEA(DST, ts_) do {                                   \
    const int kby_ = (ts_) * 128;                               \
    gload16(aRow0 + kby_, (char*)(DST) + t * 16);               \
    gload16(aRow1 + kby_, (char*)(DST) + 4096 + t * 16);        \
  } while (0)

  // ---- B direct-frag bases (r7-proven layout) ----
  const int fg0 = nt * 4 + wc * 2;  // F-group of this wave's first n-frag
  const char* bBase0 = (const char*)Wt + (size_t)(h * 64 + fg0) * 32768 + lane * 16;
  const char* bBase1 = (const char*)Wt + (size_t)(h * 64 + fg0 + 1) * 32768 + lane * 16;

  bf16x8 c00, c01, c10, c11;  // B regs for current step (ng, ksub)
  bf16x8 n00, n01, n10, n11;  // B regs for next step

#define BLOAD(P00, P01, P10, P11, ts_) do {                     \
    if ((ts_) < 16) {                                           \
      const size_t kb_ = (size_t)(ts_) * 2048;                  \
      P00 = *(const bf16x8*)(bBase0 + kb_);                     \
      P01 = *(const bf16x8*)(bBase0 + kb_ + 1024);              \
      P10 = *(const bf16x8*)(bBase1 + kb_);                     \
      P11 = *(const bf16x8*)(bBase1 + kb_ + 1024);              \
    }                                                           \
  } while (0)

  // ---- A frag read addressing (r12-proven): row*128B, XOR swz ----
  const int swz = (lane & 7) << 4;
  const int ra = (wr * 32 + (lane & 15)) * 128;
  const int kc = (lane >> 4) << 4;

  f32x4 acc00 = {0.f, 0.f, 0.f, 0.f}, acc01 = {0.f, 0.f, 0.f, 0.f};
  f32x4 acc10 = {0.f, 0.f, 0.f, 0.f}, acc11 = {0.f, 0.f, 0.f, 0.f};

#define COMPUTE(ABUF, B00, B01, B10, B11) do {                                   \
    const char* ab_ = (const char*)(ABUF);                                       \
    {                                                                            \
      const int co_ = kc ^ swz;                                                  \
      const bf16x8 a0_ = *(const bf16x8*)(ab_ + ra + co_);                       \
      const bf16x8 a1_ = *(const bf16x8*)(ab_ + ra + 2048 + co_);                \
      acc00 = __builtin_amdgcn_mfma_f32_16x16x32_bf16(a0_, B00, acc00, 0, 0, 0); \
      acc01 = __builtin_amdgcn_mfma_f32_16x16x32_bf16(a0_, B10, acc01, 0, 0, 0); \
      acc10 = __builtin_amdgcn_mfma_f32_16x16x32_bf16(a1_, B00, acc10, 0, 0, 0); \
      acc11 = __builtin_amdgcn_mfma_f32_16x16x32_bf16(a1_, B10, acc11, 0, 0, 0); \
    }                                                                            \
    {                                                                            \
      const int co_ = (64 + kc) ^ swz;                                           \
      const bf16x8 a0_ = *(const bf16x8*)(ab_ + ra + co_);                       \
      const bf16x8 a1_ = *(const bf16x8*)(ab_ + ra + 2048 + co_);                \
      acc00 = __builtin_amdgcn_mfma_f32_16x16x32_bf16(a0_, B01, acc00, 0, 0, 0); \
      acc01 = __builtin_amdgcn_mfma_f32_16x16x32_bf16(a0_, B11, acc01, 0, 0, 0); \
      acc10 = __builtin_amdgcn_mfma_f32_16x16x32_bf16(a1_, B01, acc10, 0, 0, 0); \
      acc11 = __builtin_amdgcn_mfma_f32_16x16x32_bf16(a1_, B11, acc11, 0, 0, 0); \
    }                                                                            \
  } while (0)

  // prologue: A(0) gloads, then B(0) regs; WAITV(4) drains A(0) (FIFO oldest)
  STAGEA(As0, 0);
  BLOAD(c00, c01, c10, c11, 0);
  WAITV(4);
  __builtin_amdgcn_s_barrier();
  __builtin_amdgcn_sched_barrier(0);

#pragma unroll 1
  for (int it = 0; it < 8; ++it) {
    const int ts = it * 2;
    // even step: compute(As0, c), prefetch A(ts+1)->As1, B(ts+1)->n
    if (ts + 1 < 16) STAGEA(As1, ts + 1);   // As1 readers finished at ts-1
    BLOAD(n00, n01, n10, n11, ts + 1);
    COMPUTE(As0, c00, c01, c10, c11);
    WAITV(4);                               // drain A(ts+1); B(ts+1) in flight
    __builtin_amdgcn_s_barrier();
    __builtin_amdgcn_sched_barrier(0);
    // odd step: compute(As1, n), prefetch A(ts+2)->As0, B(ts+2)->c
    if (ts + 2 < 16) STAGEA(As0, ts + 2);
    BLOAD(c00, c01, c10, c11, ts + 2);
    COMPUTE(As1, n00, n01, n10, n11);
    WAITV(4);
    __builtin_amdgcn_s_barrier();
    __builtin_amdgcn_sched_barrier(0);
  }

  // ---- epilogue: plain scatter through rows[] + bias ----
  const int jrow = (lane >> 4) * 4;
  const int ccol = lane & 15;
#pragma unroll
  for (int m = 0; m < 2; ++m) {
#pragma unroll
    for (int j = 0; j < 4; ++j) {
      const int lr = wr * 32 + m * 16 + jrow + j;
      if (m0 + lr < cnt_h) {
        const int b = rows[basep + m0 + lr];
#pragma unroll
        for (int n = 0; n < 2; ++n) {
          const int c = n0 + wc * 32 + n * 16 + ccol;
          float v;
          if (m == 0 && n == 0) v = acc00[j];
          else if (m == 0 && n == 1) v = acc01[j];
          else if (m == 1 && n == 0) v = acc10[j];
          else v = acc11[j];
          out[(size_t)b * 1024 + c] = v + bias[h * 1024 + c];
        }
      }
    }
  }
#undef STAGEA
#undef BLOAD
#undef COMPUTE
}

extern "C" void kernel_launch(void* const* d_in, const int* in_sizes, int n_in,
                              void* d_out, int out_size, void* d_ws, size_t ws_size,
                              hipStream_t stream) {
  const float* X = (const float*)d_in[0];
  const int* idx = (const int*)d_in[1];
  const float* W = (const float*)d_in[2];
  const float* bias = (const float*)d_in[3];
  float* out = (float*)d_out;

  char* ws = (char*)d_ws;
  int* cnt = (int*)ws;                                   // 8 ints @ 0
  int* base16 = (int*)(ws + 64);                         // 9 ints @ 64
  int* rows = (int*)(ws + 256);                          // 4352 ints
  unsigned short* Wt = (unsigned short*)(ws + 32768);    // 512 grp16 x 32KB = 16 MB
  unsigned short* Ap = (unsigned short*)(ws + 32768 + 16777216);  // 4352 rows * 2KB

  k_prep<<<dim3(2049), 256, 0, stream>>>(W, idx, Wt, cnt, base16, rows);
  k_gather<<<dim3(4352), 256, 0, stream>>>(X, rows, Ap);
  // 8 heads (xcd-affine) x 16 nt x 16 mt (early-return past cnt_h)
  k_gemm<<<dim3(8 * 16 * 16), 256, 0, stream>>>(Ap, Wt, rows, cnt, base16, bias, out);
}